// Round 9
// baseline (178.604 us; speedup 1.0000x reference)
//
#include <hip/hip_runtime.h>
#include <hip/hip_bf16.h>
#include <math.h>

// Sizes fixed by the reference: B=16, N=2048, F_in=F_out=64.
#define NB 16
#define NN 2048
#define NF 64
#define LOG2E 1.44269504f
#define ISPLIT 16         // colsum i-split factor
#define GRID 1024         // exactly 4 blocks/CU on 256 CUs (co-resident by construction)

// g(t) nearest-neighbor table: t in [T_LO, T_HI], NT bins, value at bin midpoint.
#define NT 4096
#define T_LO (-40.0f)
#define T_HI (10.0f)
#define T_SCALE (NT / (T_HI - T_LO))         // 81.92 bins per unit t
#define Z_BIAS (-T_LO * T_SCALE)             // 3276.8
#define Z_MAX ((float)(NT - 1))

typedef __attribute__((ext_vector_type(8))) __bf16 bf16x8;
typedef __attribute__((ext_vector_type(8))) short  short8;
typedef __attribute__((ext_vector_type(4))) float  f32x4;

// Accurate g(t) = exp(sigmoid(leakyrelu(t))) — table build only (16 evals/thread).
__device__ __forceinline__ float gexact(float t) {
    float v = t >= 0.f ? t : 0.2f * t;
    float s = 1.f / (1.f + expf(-v));
    return expf(s);
}

__device__ __forceinline__ float tlookup(const float* __restrict__ stab, float z) {
    float zc = __builtin_amdgcn_fmed3f(z, 0.f, Z_MAX);
    return stab[(int)zc];
}

__device__ __forceinline__ float elu(float v) {
    return v > 0.f ? v : (__builtin_amdgcn_exp2f(v * LOG2E) - 1.f);
}

// Software grid barrier (gen-protocol). State zeroed by hipMemsetAsync each launch.
// Safe: all GRID blocks are co-resident (LDS 25.6KB -> 6/CU, VGPR<=128 -> 4/CU, grid = 4*256).
__device__ __forceinline__ void gridbar(unsigned* cnt, unsigned* gen, unsigned nb) {
    __syncthreads();
    if (threadIdx.x == 0) {
        unsigned g = __hip_atomic_load(gen, __ATOMIC_ACQUIRE, __HIP_MEMORY_SCOPE_AGENT);
        unsigned a = __hip_atomic_fetch_add(cnt, 1u, __ATOMIC_ACQ_REL, __HIP_MEMORY_SCOPE_AGENT);
        if (a == nb - 1u) {
            __hip_atomic_store(cnt, 0u, __ATOMIC_RELAXED, __HIP_MEMORY_SCOPE_AGENT);
            __hip_atomic_store(gen, g + 1u, __ATOMIC_RELEASE, __HIP_MEMORY_SCOPE_AGENT);
        } else {
            while (__hip_atomic_load(gen, __ATOMIC_RELAXED, __HIP_MEMORY_SCOPE_AGENT) == g) {
                __builtin_amdgcn_s_sleep(1);
            }
            (void)__hip_atomic_load(gen, __ATOMIC_ACQUIRE, __HIP_MEMORY_SCOPE_AGENT);
        }
    }
    __syncthreads();
}

__global__ __launch_bounds__(256, 4) void k_fused(const float* __restrict__ h,
                                                  const float* __restrict__ W,
                                                  const float* __restrict__ a,
                                                  float* __restrict__ out,
                                                  float* __restrict__ wh,
                                                  float* __restrict__ xs,
                                                  float* __restrict__ ys,
                                                  float* __restrict__ dpart,
                                                  uint4* __restrict__ vfrag,
                                                  unsigned* __restrict__ barcnt,
                                                  unsigned* __restrict__ bargen) {
    __shared__ float stab[NT];            // 16 KB, persistent
    __shared__ float red[2][16][65];      // 8.32 KB (phase 3)
    __shared__ float scratch[288];        // 1.15 KB (hb / xb / pred+dinv)

    int bid = blockIdx.x;
    int tid = threadIdx.x;
    int w   = tid >> 6, lane = tid & 63;

    // ---- table build, local per block (overlaps nothing; ~0.3 us)
#pragma unroll
    for (int i = tid; i < NT; i += 256)
        stab[i] = gexact(T_LO + ((float)i + 0.5f) / T_SCALE);

    // ---- Phase 0: Wh = h@W ; xs = T_SCALE*(Wh@a1) ; ys = T_SCALE*(Wh@a2). 8 iters.
    float* hb = scratch;                  // [4][64], per-wave private rows
    for (int vb = bid; vb < NB * NN / 4; vb += GRID) {
        int r = vb * 4 + w;
        hb[w * 64 + lane] = h[r * 64 + lane];   // within-wave write->read, lockstep-safe
        float acc = 0.f;
#pragma unroll
        for (int k = 0; k < 64; k++) acc = fmaf(hb[w * 64 + k], W[k * 64 + lane], acc);
        wh[r * 64 + lane] = acc;
        float xv = acc * a[lane];
        float yv = acc * a[64 + lane];
#pragma unroll
        for (int m = 32; m; m >>= 1) {
            xv += __shfl_xor(xv, m, 64);
            yv += __shfl_xor(yv, m, 64);
        }
        if (lane == 0) {
            xs[r] = T_SCALE * xv;
            ys[r] = T_SCALE * yv;
        }
    }
    gridbar(barcnt, bargen, GRID);

    // ---- Phase 1: column-sum partials dpart[isp][b][j] over 128 i's each. 2 iters.
    float* xb = scratch;                  // [128]
    for (int vb = bid; vb < NB * ISPLIT * (NN / 256); vb += GRID) {
        int jb  = vb & 7;
        int isp = (vb >> 3) & 15;
        int b   = vb >> 7;
        __syncthreads();
        if (tid < 128) xb[tid] = xs[b * NN + isp * 128 + tid];
        __syncthreads();
        float ypre = ys[b * NN + jb * 256 + tid] + Z_BIAS;
        float acc = 0.f;
#pragma unroll 4
        for (int i4 = 0; i4 < 32; i4++) {
            float4 xv = *reinterpret_cast<const float4*>(&xb[i4 * 4]);
            acc += tlookup(stab, xv.x + ypre);
            acc += tlookup(stab, xv.y + ypre);
            acc += tlookup(stab, xv.z + ypre);
            acc += tlookup(stab, xv.w + ypre);
        }
        dpart[isp * (NB * NN) + b * NN + jb * 256 + tid] = acc;
    }
    gridbar(barcnt, bargen, GRID);

    // ---- Phase 2: D-reduce + V-frag. Exactly 1 virtual block per block.
    {
        float* pred = scratch;            // [8][32]
        float* dinv = scratch + 256;      // [32]
        int ks = bid & 63;
        int b  = bid >> 6;
        {
            int p = tid >> 5, r2 = tid & 31;
            int rowg = b * NN + ks * 32 + r2;
            pred[p * 32 + r2] = dpart[p * (NB * NN) + rowg] + dpart[(p + 8) * (NB * NN) + rowg];
        }
        __syncthreads();
        if (tid < 32) {
            float s = 0.f;
#pragma unroll
            for (int p2 = 0; p2 < 8; p2++) s += pred[p2 * 32 + tid];
            dinv[tid] = __builtin_amdgcn_rcpf(s);
        }
        __syncthreads();
        int nt = w, kg = lane >> 4, il = lane & 15;
        const float* whp = wh + (b * NN + ks * 32 + kg * 8) * 64 + nt * 16 + il;
        short8 o;
#pragma unroll
        for (int e = 0; e < 8; e++) {
            float v   = whp[e * 64] * dinv[kg * 8 + e];
            __bf16 bv = (__bf16)v;
            o[e]      = __builtin_bit_cast(short, bv);
        }
        vfrag[((b * 64 + ks) * 4 + nt) * 64 + lane] = __builtin_bit_cast(uint4, o);
    }
    gridbar(barcnt, bargen, GRID);

    // ---- Phase 3: out = ELU( E @ V ), 32 rows per block. Exactly 1 virtual block per block.
    // A-frag (16x32): row = lane&15, k = (lane>>4)*8 + e
    // C/D frag:       col = lane&15, row = (lane>>4)*4 + reg
    {
        int b  = bid >> 6;
        int ib = bid & 63;
        int rg = w & 1, kz = w >> 1;
        int il = lane & 15, kg = lane >> 4;
        int ibase = ib * 32 + rg * 16;

        float xv = xs[b * NN + ibase + il] + Z_BIAS;
        const float* ysb = ys + b * NN;
        const uint4* vfb = vfrag + b * 16384 + lane;

        f32x4 acc0 = {0.f, 0.f, 0.f, 0.f};
        f32x4 acc1 = {0.f, 0.f, 0.f, 0.f};
        f32x4 acc2 = {0.f, 0.f, 0.f, 0.f};
        f32x4 acc3 = {0.f, 0.f, 0.f, 0.f};

        for (int ks = kz * 32; ks < kz * 32 + 32; ks++) {
            const float* yp = ysb + ks * 32 + kg * 8;
            float4 ya = *reinterpret_cast<const float4*>(yp);
            float4 yb = *reinterpret_cast<const float4*>(yp + 4);
            float wv[8];
            wv[0] = tlookup(stab, xv + ya.x);
            wv[1] = tlookup(stab, xv + ya.y);
            wv[2] = tlookup(stab, xv + ya.z);
            wv[3] = tlookup(stab, xv + ya.w);
            wv[4] = tlookup(stab, xv + yb.x);
            wv[5] = tlookup(stab, xv + yb.y);
            wv[6] = tlookup(stab, xv + yb.z);
            wv[7] = tlookup(stab, xv + yb.w);
            bf16x8 af;
#pragma unroll
            for (int e = 0; e < 8; e++) af[e] = (__bf16)wv[e];

            const uint4* vp = vfb + ks * 256;
            bf16x8 b0 = __builtin_bit_cast(bf16x8, vp[0]);
            bf16x8 b1 = __builtin_bit_cast(bf16x8, vp[64]);
            bf16x8 b2 = __builtin_bit_cast(bf16x8, vp[128]);
            bf16x8 b3 = __builtin_bit_cast(bf16x8, vp[192]);

            acc0 = __builtin_amdgcn_mfma_f32_16x16x32_bf16(af, b0, acc0, 0, 0, 0);
            acc1 = __builtin_amdgcn_mfma_f32_16x16x32_bf16(af, b1, acc1, 0, 0, 0);
            acc2 = __builtin_amdgcn_mfma_f32_16x16x32_bf16(af, b2, acc2, 0, 0, 0);
            acc3 = __builtin_amdgcn_mfma_f32_16x16x32_bf16(af, b3, acc3, 0, 0, 0);
        }

        if (kz == 1) {
#pragma unroll
            for (int r = 0; r < 4; r++) {
                float* rp = &red[rg][kg * 4 + r][il];
                rp[0]  = acc0[r];
                rp[16] = acc1[r];
                rp[32] = acc2[r];
                rp[48] = acc3[r];
            }
        }
        __syncthreads();
        if (kz == 0) {
            int rbase = b * NN + ibase + kg * 4;
#pragma unroll
            for (int r = 0; r < 4; r++) {
                const float* r0 = &red[rg][kg * 4 + r][il];
                float* orow = out + (rbase + r) * 64 + il;
                orow[0]  = elu(acc0[r] + r0[0]);
                orow[16] = elu(acc1[r] + r0[16]);
                orow[32] = elu(acc2[r] + r0[32]);
                orow[48] = elu(acc3[r] + r0[48]);
            }
        }
    }
}

extern "C" void kernel_launch(void* const* d_in, const int* in_sizes, int n_in,
                              void* d_out, int out_size, void* d_ws, size_t ws_size,
                              hipStream_t stream) {
    const float* h = (const float*)d_in[0];
    const float* W = (const float*)d_in[1];
    const float* a = (const float*)d_in[2];
    float* out = (float*)d_out;

    // workspace layout (floats), ~15 MB total
    float*  wh    = (float*)d_ws;                  // B*N*64   = 2,097,152 f
    float*  xs    = wh + NB * NN * NF;             // B*N      =    32,768 f
    float*  ys    = xs + NB * NN;                  // B*N
    float*  dpart = ys + NB * NN;                  // 16*B*N   =   524,288 f
    uint4*  vfrag = (uint4*)(dpart + ISPLIT * NB * NN);  // B*N*64 bf16 = 4 MB
    unsigned* bar = (unsigned*)(vfrag + NB * NN * NF / 8);  // cnt @0, gen @64

    hipMemsetAsync(bar, 0, 512, stream);
    k_fused<<<dim3(GRID), dim3(256), 0, stream>>>(h, W, a, out, wh, xs, ys, dpart,
                                                  vfrag, bar, bar + 64);
}

// Round 10
// 72.913 us; speedup vs baseline: 2.4496x; 2.4496x over previous
//
#include <hip/hip_runtime.h>
#include <hip/hip_bf16.h>
#include <math.h>

// Sizes fixed by the reference: B=16, N=2048, F_in=F_out=64.
#define NB 16
#define NN 2048
#define NF 64
#define LOG2E 1.44269504f
#define ISPLIT 16         // k_colsum i-split factor

// g(t) nearest-neighbor table: t in [T_LO, T_HI], NT bins, value at bin midpoint.
#define NT 4096
#define T_LO (-40.0f)
#define T_HI (10.0f)
#define T_SCALE (NT / (T_HI - T_LO))         // 81.92 bins per unit t
#define Z_BIAS (-T_LO * T_SCALE)             // 3276.8
#define Z_MAX ((float)(NT - 1))

typedef __attribute__((ext_vector_type(8))) __bf16 bf16x8;
typedef __attribute__((ext_vector_type(8))) short  short8;
typedef __attribute__((ext_vector_type(4))) float  f32x4;

// Accurate g(t) = exp(sigmoid(leakyrelu(t))) — table build only.
__device__ __forceinline__ float gexact(float t) {
    float v = t >= 0.f ? t : 0.2f * t;
    float s = 1.f / (1.f + expf(-v));
    return expf(s);
}

// Exact trans-pipe eval from tp = -log2e * t (verified R1-R4).
// u = min(tp, 0.2*tp) = -log2e*leaky(t); e^s via exp2.
__device__ __forceinline__ float evalg(float tp) {
    float u  = fminf(tp, 0.2f * tp);
    float ex = __builtin_amdgcn_exp2f(u);              // e^{-leaky}
    float s  = __builtin_amdgcn_rcpf(1.f + ex);        // sigmoid(leaky)
    return __builtin_amdgcn_exp2f(s * LOG2E);          // e^{sigmoid}
}

// LDS-pipe eval: z = t*T_SCALE + Z_BIAS (scale/bias pre-folded by caller).
__device__ __forceinline__ float tlookup(const float* __restrict__ stab, float z) {
    float zc = __builtin_amdgcn_fmed3f(z, 0.f, Z_MAX);
    return stab[(int)zc];
}

__device__ __forceinline__ float elu(float v) {
    return v > 0.f ? v : (__builtin_amdgcn_exp2f(v * LOG2E) - 1.f);
}

// ---------------- Pass A: Wh = h@W ; score pre-activations in BOTH domains:
// xs,ys = T_SCALE*t (z-domain, table) ; xs2,ys2 = -LOG2E*t (tp-domain, trans).
// Blocks 0..15 additionally build the g-table.
__global__ __launch_bounds__(256) void k_prep(const float* __restrict__ h,
                                              const float* __restrict__ W,
                                              const float* __restrict__ a,
                                              float* __restrict__ wh,
                                              float* __restrict__ xs,
                                              float* __restrict__ ys,
                                              float* __restrict__ xs2,
                                              float* __restrict__ ys2,
                                              float* __restrict__ gtab) {
    __shared__ float hb[4][64];
    int w = threadIdx.x >> 6, lane = threadIdx.x & 63;
    int r = blockIdx.x * 4 + w;                 // row in [0, B*N)
    hb[w][lane] = h[r * 64 + lane];
    float acc = 0.f;
#pragma unroll
    for (int k = 0; k < 64; k++) acc = fmaf(hb[w][k], W[k * 64 + lane], acc);
    wh[r * 64 + lane] = acc;
    float xv = acc * a[lane];
    float yv = acc * a[64 + lane];
#pragma unroll
    for (int m = 32; m; m >>= 1) {
        xv += __shfl_xor(xv, m, 64);
        yv += __shfl_xor(yv, m, 64);
    }
    if (lane == 0) {
        xs[r]  = T_SCALE * xv;
        ys[r]  = T_SCALE * yv;
        xs2[r] = -LOG2E * xv;
        ys2[r] = -LOG2E * yv;
    }
    if (blockIdx.x < 16) {
        int i = blockIdx.x * 256 + threadIdx.x;     // [0, 4096)
        gtab[i] = gexact(T_LO + ((float)i + 0.5f) / T_SCALE);
    }
}

// ---------------- Pass B: column-sum partials, pipe-balanced eval:
// even i4-groups via LDS table, odd i4-groups via trans pipe.
__global__ __launch_bounds__(256) void k_colsum(const float* __restrict__ xs,
                                                const float* __restrict__ ys,
                                                const float* __restrict__ xs2,
                                                const float* __restrict__ ys2,
                                                const float* __restrict__ gtab,
                                                float* __restrict__ dpart) {
    __shared__ float stab[NT];
    __shared__ float xb[128];      // z-domain
    __shared__ float xb2[128];     // tp-domain
    int tid = threadIdx.x;
    {   // stage table (16 KB) into LDS
        const float4* src = (const float4*)gtab;
        float4*       dst = (float4*)stab;
#pragma unroll
        for (int k = 0; k < NT / 4 / 256; k++) dst[tid + k * 256] = src[tid + k * 256];
    }
    int bx  = blockIdx.x;
    int jb  = bx & 7;            // N/256 = 8 j-chunks
    int isp = (bx >> 3) & 15;    // 16-way i split (128 i's each)
    int b   = bx >> 7;
    if (tid < 128) {
        xb[tid]  = xs[b * NN + isp * 128 + tid];
        xb2[tid] = xs2[b * NN + isp * 128 + tid];
    }
    __syncthreads();
    float ypre  = ys[b * NN + jb * 256 + tid] + Z_BIAS;   // z-domain
    float yv2   = ys2[b * NN + jb * 256 + tid];           // tp-domain
    float acc = 0.f;
#pragma unroll 4
    for (int i8 = 0; i8 < 16; i8++) {
        float4 xa = *reinterpret_cast<const float4*>(&xb[i8 * 8]);       // table half
        float4 xc = *reinterpret_cast<const float4*>(&xb2[i8 * 8 + 4]);  // trans half
        acc += tlookup(stab, xa.x + ypre);
        acc += tlookup(stab, xa.y + ypre);
        acc += tlookup(stab, xa.z + ypre);
        acc += tlookup(stab, xa.w + ypre);
        acc += evalg(xc.x + yv2);
        acc += evalg(xc.y + yv2);
        acc += evalg(xc.z + yv2);
        acc += evalg(xc.w + yv2);
    }
    dpart[isp * (NB * NN) + b * NN + jb * 256 + tid] = acc;
}

// ---------------- Pass B2 (fused D-reduce + V-frag): block per (b, ks) handles 32 rows.
// vfrag layout: [b][ks(64)][nt(4)][lane(64)] x 8 bf16; B-frag: col = lane&15, k = (lane>>4)*8 + e
__global__ __launch_bounds__(256) void k_vfragD(const float* __restrict__ wh,
                                                const float* __restrict__ dpart,
                                                uint4* __restrict__ vfrag) {
    __shared__ float pred[8][32];
    __shared__ float dinv[32];
    int bx = blockIdx.x;
    int ks = bx & 63;
    int b  = bx >> 6;
    int t  = threadIdx.x;
    {   // stage 1: 16 partials -> 8 in LDS
        int p = t >> 5, r = t & 31;
        int rowg = b * NN + ks * 32 + r;
        pred[p][r] = dpart[p * (NB * NN) + rowg] + dpart[(p + 8) * (NB * NN) + rowg];
    }
    __syncthreads();
    if (t < 32) {   // stage 2: finish the sum, invert
        float s = 0.f;
#pragma unroll
        for (int p2 = 0; p2 < 8; p2++) s += pred[p2][t];
        dinv[t] = __builtin_amdgcn_rcpf(s);
    }
    __syncthreads();
    int lane = t & 63, nt = t >> 6;
    int kg = lane >> 4, il = lane & 15;
    const float* whp = wh + (b * NN + ks * 32 + kg * 8) * 64 + nt * 16 + il;
    short8 o;
#pragma unroll
    for (int e = 0; e < 8; e++) {
        float v   = whp[e * 64] * dinv[kg * 8 + e];
        __bf16 bv = (__bf16)v;
        o[e]      = __builtin_bit_cast(short, bv);
    }
    vfrag[((b * 64 + ks) * 4 + nt) * 64 + lane] = __builtin_bit_cast(uint4, o);
}

// ---------------- Pass C: out = ELU( E @ V ), 32 rows per block for V-reuse.
// Per K-step: evals 0-3 via table (ya from ys), evals 4-7 via trans (yb2 from ys2).
// A-frag (16x32): row = lane&15, k = (lane>>4)*8 + e
// C/D frag:       col = lane&15, row = (lane>>4)*4 + reg   [verified layout]
__global__ __launch_bounds__(256) void k_attn(const float* __restrict__ xs,
                                              const float* __restrict__ ys,
                                              const float* __restrict__ xs2,
                                              const float* __restrict__ ys2,
                                              const float* __restrict__ gtab,
                                              const uint4* __restrict__ vfrag,
                                              float* __restrict__ out) {
    __shared__ float stab[NT];
    __shared__ float red[2][16][65];   // [rg][local row][col(+pad)]
    {   // stage table (16 KB) into LDS
        const float4* src = (const float4*)gtab;
        float4*       dst = (float4*)stab;
#pragma unroll
        for (int k = 0; k < NT / 4 / 256; k++) dst[threadIdx.x + k * 256] = src[threadIdx.x + k * 256];
    }
    int b  = blockIdx.x >> 6;          // batch
    int ib = blockIdx.x & 63;          // 64 i-blocks of 32 rows
    int w  = threadIdx.x >> 6, lane = threadIdx.x & 63;
    int rg = w & 1, kz = w >> 1;
    int il = lane & 15, kg = lane >> 4;
    int ibase = ib * 32 + rg * 16;

    float xv  = xs[b * NN + ibase + il] + Z_BIAS;   // z-domain
    float xv2 = xs2[b * NN + ibase + il];           // tp-domain
    const float* ysb  = ys + b * NN;
    const float* ysb2 = ys2 + b * NN;
    const uint4* vfb  = vfrag + b * 16384 + lane;
    __syncthreads();

    f32x4 acc0 = {0.f, 0.f, 0.f, 0.f};
    f32x4 acc1 = {0.f, 0.f, 0.f, 0.f};
    f32x4 acc2 = {0.f, 0.f, 0.f, 0.f};
    f32x4 acc3 = {0.f, 0.f, 0.f, 0.f};

    for (int ks = kz * 32; ks < kz * 32 + 32; ks++) {
        const float* yp  = ysb  + ks * 32 + kg * 8;
        const float* yp2 = ysb2 + ks * 32 + kg * 8;
        float4 ya  = *reinterpret_cast<const float4*>(yp);       // k +0..3 (table)
        float4 yb2 = *reinterpret_cast<const float4*>(yp2 + 4);  // k +4..7 (trans)
        float wv[8];
        wv[0] = tlookup(stab, xv + ya.x);
        wv[1] = tlookup(stab, xv + ya.y);
        wv[2] = tlookup(stab, xv + ya.z);
        wv[3] = tlookup(stab, xv + ya.w);
        wv[4] = evalg(xv2 + yb2.x);
        wv[5] = evalg(xv2 + yb2.y);
        wv[6] = evalg(xv2 + yb2.z);
        wv[7] = evalg(xv2 + yb2.w);
        bf16x8 af;
#pragma unroll
        for (int e = 0; e < 8; e++) af[e] = (__bf16)wv[e];

        const uint4* vp = vfb + ks * 256;
        bf16x8 b0 = __builtin_bit_cast(bf16x8, vp[0]);
        bf16x8 b1 = __builtin_bit_cast(bf16x8, vp[64]);
        bf16x8 b2 = __builtin_bit_cast(bf16x8, vp[128]);
        bf16x8 b3 = __builtin_bit_cast(bf16x8, vp[192]);

        acc0 = __builtin_amdgcn_mfma_f32_16x16x32_bf16(af, b0, acc0, 0, 0, 0);
        acc1 = __builtin_amdgcn_mfma_f32_16x16x32_bf16(af, b1, acc1, 0, 0, 0);
        acc2 = __builtin_amdgcn_mfma_f32_16x16x32_bf16(af, b2, acc2, 0, 0, 0);
        acc3 = __builtin_amdgcn_mfma_f32_16x16x32_bf16(af, b3, acc3, 0, 0, 0);
    }

    if (kz == 1) {
#pragma unroll
        for (int r = 0; r < 4; r++) {
            float* rp = &red[rg][kg * 4 + r][il];
            rp[0]  = acc0[r];
            rp[16] = acc1[r];
            rp[32] = acc2[r];
            rp[48] = acc3[r];
        }
    }
    __syncthreads();
    if (kz == 0) {
        int rbase = b * NN + ibase + kg * 4;
#pragma unroll
        for (int r = 0; r < 4; r++) {
            const float* r0 = &red[rg][kg * 4 + r][il];
            float* orow = out + (rbase + r) * 64 + il;
            orow[0]  = elu(acc0[r] + r0[0]);
            orow[16] = elu(acc1[r] + r0[16]);
            orow[32] = elu(acc2[r] + r0[32]);
            orow[48] = elu(acc3[r] + r0[48]);
        }
    }
}

extern "C" void kernel_launch(void* const* d_in, const int* in_sizes, int n_in,
                              void* d_out, int out_size, void* d_ws, size_t ws_size,
                              hipStream_t stream) {
    const float* h = (const float*)d_in[0];
    const float* W = (const float*)d_in[1];
    const float* a = (const float*)d_in[2];
    float* out = (float*)d_out;

    // workspace layout (floats), ~15.5 MB total
    float*  wh    = (float*)d_ws;                  // B*N*64   = 2,097,152 f
    float*  xs    = wh + NB * NN * NF;             // B*N
    float*  ys    = xs + NB * NN;                  // B*N
    float*  xs2   = ys + NB * NN;                  // B*N
    float*  ys2   = xs2 + NB * NN;                 // B*N
    float*  dpart = ys2 + NB * NN;                 // 16*B*N
    uint4*  vfrag = (uint4*)(dpart + ISPLIT * NB * NN);  // B*N*64 bf16 = 4 MB
    float*  gtab  = (float*)(vfrag + NB * NN * NF / 8);  // 4096 f32 = 16 KB

    k_prep<<<dim3(NB * NN / 4), dim3(256), 0, stream>>>(h, W, a, wh, xs, ys, xs2, ys2, gtab);
    k_colsum<<<dim3(NB * ISPLIT * (NN / 256)), dim3(256), 0, stream>>>(xs, ys, xs2, ys2, gtab, dpart);
    k_vfragD<<<dim3(NB * 64), dim3(256), 0, stream>>>(wh, dpart, vfrag);
    k_attn<<<dim3(NB * (NN / 32)), dim3(256), 0, stream>>>(xs, ys, xs2, ys2, gtab, vfrag, out);
}